// Round 5
// baseline (175.015 us; speedup 1.0000x reference)
//
#include <hip/hip_runtime.h>

// Reference: H=16, TP=8, C=257, T=S=128.  Output float32 (T,S,C,TP).
// d = sign(c1)sign(c2) * norm * (clz(xor+1) - 16) / 16   (exact; r1==r2 verified)
//
// Round 5 = MEASUREMENT ROUND. Same structure as round 4, but every store is
// mirrored into d_ws at the same offset (same stride/alignment pattern, 2x
// write volume). If the write path is inefficient, the doubled kernel crosses
// the top-5 rocprof cutoff and we finally get its counter row.

namespace {
constexpr int kTP   = 8;
constexpr int kC    = 257;
constexpr int kT    = 128;
constexpr int kS    = 128;
constexpr int kSB   = 8;              // s per block
constexpr int kTile = kS / kSB;       // 16 s-tiles per t

typedef __attribute__((ext_vector_type(4))) int   int4v;
typedef __attribute__((ext_vector_type(4))) float float4v;
} // namespace

__global__ __launch_bounds__(256) void critigraph_kernel(
    const int*   __restrict__ sta,   // (T,TP)
    const int*   __restrict__ pos,   // (T,S,TP)
    const int*   __restrict__ cnc,   // (T,C,TP)
    const float* __restrict__ eu,    // (T,S)
    float*       __restrict__ out,   // (T,S,C,TP) f32
    float*       __restrict__ mir)   // mirror target (d_ws or out)
{
    __shared__ int   s_apos[kSB][kTP];
    __shared__ float s_np8[kSB][kTP];
    __shared__ float s_csp[kSB][kTP];
    __shared__ float s_base8[kSB][kTP];

    const int t   = blockIdx.x >> 4;
    const int s0  = (blockIdx.x & (kTile - 1)) * kSB;
    const int tid = threadIdx.x;

    if (tid < kSB * kTP) {
        const int sl = tid >> 3;
        const int p  = tid & 7;
        const int s  = s0 + sl;
        const int st = sta[t * kTP + p];
        const int po = pos[(t * kS + s) * kTP + p];
        const float norm = eu[t * kS + s];
        const int x = (abs(st) ^ abs(po)) + 1;
        const float f = (float)(__clz(x) - 16);
        const float v = f * norm * (1.0f / 16.0f);
        s_csp[sl][p]  = ((st ^ po) < 0) ? -v : v;
        s_apos[sl][p] = abs(po);
        s_np8[sl][p]  = (po >= 0 ? norm : -norm) * (1.0f / 128.0f);
    }
    __syncthreads();
    if (tid < kSB * kTP) {
        const int sl = tid >> 3;
        const int p  = tid & 7;
        float sum = 0.0f;
#pragma unroll
        for (int q = 0; q < kTP; ++q) sum += s_csp[sl][q];
        s_base8[sl][p] = (sum - s_csp[sl][p]) * 0.125f;
    }
    __syncthreads();

    // ---- main: candidate c = tid ----
    {
        const int c = tid;
        const int* cb = cnc + ((size_t)t * kC + c) * kTP;
        const int4v lo = *(const int4v*)cb;
        const int4v hi = *(const int4v*)(cb + 4);
        int      acn[kTP];
        unsigned sg[kTP];
#pragma unroll
        for (int p = 0; p < kTP; ++p) {
            const int cn = (p < 4) ? lo[p] : hi[p - 4];
            acn[p] = abs(cn);
            sg[p]  = ((unsigned)cn) & 0x80000000u;
        }

        const size_t off0 = ((size_t)(t * kS + s0) * kC + c) * kTP;
        float* ob = out + off0;
        float* mb = mir + off0;
#pragma unroll
        for (int sl = 0; sl < kSB; ++sl) {
            const int4v   ap0 = *(const int4v*)&s_apos[sl][0];
            const int4v   ap1 = *(const int4v*)&s_apos[sl][4];
            const float4v np0 = *(const float4v*)&s_np8[sl][0];
            const float4v np1 = *(const float4v*)&s_np8[sl][4];
            const float4v b0  = *(const float4v*)&s_base8[sl][0];
            const float4v b1  = *(const float4v*)&s_base8[sl][4];

            float4v r0, r1;
#pragma unroll
            for (int p = 0; p < 4; ++p) {
                const int x = (acn[p] ^ ap0[p]) + 1;
                const float f = (float)(__clz(x) - 16);
                const float coeff = __int_as_float(__float_as_int(np0[p]) ^ sg[p]);
                r0[p] = fmaf(f, coeff, b0[p]);
            }
#pragma unroll
            for (int p = 0; p < 4; ++p) {
                const int x = (acn[p + 4] ^ ap1[p]) + 1;
                const float f = (float)(__clz(x) - 16);
                const float coeff = __int_as_float(__float_as_int(np1[p]) ^ sg[p + 4]);
                r1[p] = fmaf(f, coeff, b1[p]);
            }
            *(float4v*)ob       = r0;
            *(float4v*)(ob + 4) = r1;
            *(float4v*)mb       = r0;   // mirror: same pattern, 2x volume
            *(float4v*)(mb + 4) = r1;
            ob += (size_t)kC * kTP;
            mb += (size_t)kC * kTP;
        }
    }

    // ---- tail: candidate c = 256, lanes 0..7 ----
    if (tid < kTP) {
        const int p  = tid;
        const int cn = cnc[((size_t)t * kC + (kC - 1)) * kTP + p];
        const int a  = abs(cn);
        const unsigned sg = ((unsigned)cn) & 0x80000000u;
        const size_t off0 = ((size_t)(t * kS + s0) * kC + (kC - 1)) * kTP + p;
#pragma unroll
        for (int sl = 0; sl < kSB; ++sl) {
            const int x = (a ^ s_apos[sl][p]) + 1;
            const float f = (float)(__clz(x) - 16);
            const float coeff = __int_as_float(__float_as_int(s_np8[sl][p]) ^ sg);
            const float v = fmaf(f, coeff, s_base8[sl][p]);
            out[off0 + (size_t)sl * kC * kTP] = v;
            mir[off0 + (size_t)sl * kC * kTP] = v;
        }
    }
}

extern "C" void kernel_launch(void* const* d_in, const int* in_sizes, int n_in,
                              void* d_out, int out_size, void* d_ws, size_t ws_size,
                              hipStream_t stream) {
    const int*   sta = (const int*)d_in[0];
    const int*   pos = (const int*)d_in[1];
    const int*   cnc = (const int*)d_in[2];
    const float* eu  = (const float*)d_in[3];
    float*       out = (float*)d_out;

    // Mirror into workspace if it fits (host-constant branch, graph-safe);
    // otherwise mirror onto out itself (idempotent rewrite, still correct).
    const size_t need = (size_t)out_size * sizeof(float);
    float* mir = (ws_size >= need) ? (float*)d_ws : out;

    const dim3 grid(kT * kTile);
    const dim3 block(256);
    critigraph_kernel<<<grid, block, 0, stream>>>(sta, pos, cnc, eu, out, mir);
}